// Round 4
// baseline (35.657 us; speedup 1.0000x reference)
//
#include <hip/hip_runtime.h>

// UpsampleFlow2: Gaussian Nadaraya-Watson upsampling.
// out [B,3,N] = (sum_s k*f)/(sum_s k), k = exp(-|x-y|^2/r^2).
// exp(-|x|^2/r^2) cancels in num/den ->
//   k' = exp2( c2*dot(x,y) + cy*|y|^2 ),  c2=2*log2e/r^2, cy=-log2e/r^2.
// Staged per s: a = (c2*yx, c2*yy, c2*yz, cy*|y|^2), f = (fx,fy,fz,1-slot).
// dot folds bias: e = fma(px,ax, fma(py,ay, fma(pz,az, aw))) -> exp2(e).
//
// R4 theory: cost ~ per-wave-t broadcast memory ops (R1 PPT=4: 32us,
// R2 PPT=2: 38us, R3 global-load path: 33us). Amortize: PPT=8 halves R1's
// LDS traffic (131K wave-t x 2 ds_read_b128 = 5.1us pipe) and pack VALU as
// float2 pairs -> v_pk_fma_f32 (~3.8us). 2 kernels only.

typedef float v2f __attribute__((ext_vector_type(2)));

constexpr int B_ = 4, N_ = 8192, S_ = 2048;
constexpr int BLOCK = 256, PPT = 8, NPAIR = PPT / 2;
constexpr int PTS_PER_BLOCK = BLOCK * PPT;      // 2048
constexpr int NBPB = N_ / PTS_PER_BLOCK;        // 4
constexpr int NB = B_ * NBPB;                   // 16
constexpr int BN = B_ * N_;                     // 32768
constexpr float LOG2E = 1.4426950408889634f;

template <int CHUNK>
__global__ __launch_bounds__(BLOCK, 2) void uf2_main(
    const float* __restrict__ xyz,
    const float* __restrict__ sxyz,
    const float* __restrict__ sflow,
    const int* __restrict__ resol,
    float4* __restrict__ part)
{
    __shared__ float4 As[CHUNK];   // (c2*yx, c2*yy, c2*yz, cy*|y|^2)
    __shared__ float4 Fs[CHUNK];   // (fx, fy, fz, unused)

    const int nb = blockIdx.x % NB;
    const int sc = blockIdx.x / NB;
    const int b  = nb / NBPB;
    const int n0 = (nb % NBPB) * PTS_PER_BLOCK;
    const int s0 = sc * CHUNK;

    const float r = (float)resol[0];            // INITIAL_RADIUS(=1)*resol
    const float inv_r2 = 1.0f / (r * r);
    const float c2 = 2.0f * inv_r2 * LOG2E;
    const float cy = -inv_r2 * LOG2E;

    // ---- stage + pack sparse chunk into LDS ----
    const float* yb = sxyz  + b * 3 * S_;
    const float* fb = sflow + b * 3 * S_;
    for (int t = threadIdx.x; t < CHUNK; t += BLOCK) {
        const int s = s0 + t;
        const float yx = yb[s], yy = yb[S_ + s], yz = yb[2 * S_ + s];
        const float fx = fb[s], fy = fb[S_ + s], fz = fb[2 * S_ + s];
        As[t] = make_float4(c2 * yx, c2 * yy, c2 * yz,
                            cy * (yx * yx + yy * yy + yz * yz));
        Fs[t] = make_float4(fx, fy, fz, 0.0f);
    }
    __syncthreads();

    // ---- per-thread query points, paired for v_pk_fma_f32 ----
    const float* xb = xyz + b * 3 * N_;
    v2f px[NPAIR], py[NPAIR], pz[NPAIR];
    v2f acx[NPAIR], acy[NPAIR], acz[NPAIR], acw[NPAIR];
#pragma unroll
    for (int q = 0; q < NPAIR; ++q) {
        const int na = n0 + threadIdx.x + (2 * q) * BLOCK;
        const int nbp = na + BLOCK;
        px[q] = (v2f){xb[na], xb[nbp]};
        py[q] = (v2f){xb[N_ + na], xb[N_ + nbp]};
        pz[q] = (v2f){xb[2 * N_ + na], xb[2 * N_ + nbp]};
        acx[q] = (v2f){0.f, 0.f}; acy[q] = (v2f){0.f, 0.f};
        acz[q] = (v2f){0.f, 0.f}; acw[q] = (v2f){0.f, 0.f};
    }

    // ---- main loop: 2 broadcast ds_read_b128 + packed math per t ----
#pragma unroll 2
    for (int t = 0; t < CHUNK; ++t) {
        const float4 a = As[t];
        const float4 f = Fs[t];
        const v2f ax = (v2f){a.x, a.x}, ay = (v2f){a.y, a.y};
        const v2f az = (v2f){a.z, a.z}, aw = (v2f){a.w, a.w};
        const v2f fx = (v2f){f.x, f.x}, fy = (v2f){f.y, f.y};
        const v2f fz = (v2f){f.z, f.z};
#pragma unroll
        for (int q = 0; q < NPAIR; ++q) {
            v2f e = __builtin_elementwise_fma(pz[q], az, aw);
            e = __builtin_elementwise_fma(py[q], ay, e);
            e = __builtin_elementwise_fma(px[q], ax, e);
            v2f k;
            k.x = __builtin_amdgcn_exp2f(e.x);
            k.y = __builtin_amdgcn_exp2f(e.y);
            acx[q] = __builtin_elementwise_fma(k, fx, acx[q]);
            acy[q] = __builtin_elementwise_fma(k, fy, acy[q]);
            acz[q] = __builtin_elementwise_fma(k, fz, acz[q]);
            acw[q] += k;
        }
    }

    // ---- write partials (coalesced float4) ----
#pragma unroll
    for (int q = 0; q < NPAIR; ++q) {
        const int ga = b * N_ + n0 + threadIdx.x + (2 * q) * BLOCK;
        part[(size_t)sc * BN + ga] =
            make_float4(acx[q].x, acy[q].x, acz[q].x, acw[q].x);
        part[(size_t)sc * BN + ga + BLOCK] =
            make_float4(acx[q].y, acy[q].y, acz[q].y, acw[q].y);
    }
}

__global__ __launch_bounds__(BLOCK) void uf2_combine(
    const float4* __restrict__ part, float* __restrict__ out, int SC)
{
    const int g = blockIdx.x * BLOCK + threadIdx.x;   // 0..BN-1
    float4 s = make_float4(0.f, 0.f, 0.f, 0.f);
    for (int c = 0; c < SC; ++c) {
        const float4 p = part[(size_t)c * BN + g];
        s.x += p.x; s.y += p.y; s.z += p.z; s.w += p.w;
    }
    const float inv = 1.0f / s.w;
    const int b = g >> 13;            // /8192
    const int n = g & (N_ - 1);
    float* ob = out + b * 3 * N_;
    ob[n]          = s.x * inv;
    ob[N_ + n]     = s.y * inv;
    ob[2 * N_ + n] = s.z * inv;
}

// Fallback (ws too small): single kernel, full S staged in LDS, direct out.
__global__ __launch_bounds__(BLOCK, 1) void uf2_fused(
    const float* __restrict__ xyz,
    const float* __restrict__ sxyz,
    const float* __restrict__ sflow,
    const int* __restrict__ resol,
    float* __restrict__ out)
{
    constexpr int FPPT = 4;
    constexpr int PTS = BLOCK * FPPT;
    __shared__ float4 As[S_];
    __shared__ float4 Fs[S_];

    const int nb = blockIdx.x;
    const int b  = nb / (N_ / PTS);
    const int n0 = (nb % (N_ / PTS)) * PTS;

    const float r = (float)resol[0];
    const float inv_r2 = 1.0f / (r * r);
    const float c2 = 2.0f * inv_r2 * LOG2E;
    const float cy = -inv_r2 * LOG2E;

    const float* yb = sxyz  + b * 3 * S_;
    const float* fb = sflow + b * 3 * S_;
    for (int t = threadIdx.x; t < S_; t += BLOCK) {
        const float yx = yb[t], yy = yb[S_ + t], yz = yb[2 * S_ + t];
        const float fx = fb[t], fy = fb[S_ + t], fz = fb[2 * S_ + t];
        As[t] = make_float4(c2 * yx, c2 * yy, c2 * yz,
                            cy * (yx * yx + yy * yy + yz * yz));
        Fs[t] = make_float4(fx, fy, fz, 0.0f);
    }
    __syncthreads();

    const float* xb = xyz + b * 3 * N_;
    float px[FPPT], py[FPPT], pz[FPPT];
    float4 acc[FPPT];
#pragma unroll
    for (int p = 0; p < FPPT; ++p) {
        const int n = n0 + threadIdx.x + p * BLOCK;
        px[p] = xb[n]; py[p] = xb[N_ + n]; pz[p] = xb[2 * N_ + n];
        acc[p] = make_float4(0.f, 0.f, 0.f, 0.f);
    }
#pragma unroll 4
    for (int t = 0; t < S_; ++t) {
        const float4 a = As[t];
        const float4 f = Fs[t];
#pragma unroll
        for (int p = 0; p < FPPT; ++p) {
            float e = fmaf(pz[p], a.z, a.w);
            e = fmaf(py[p], a.y, e);
            e = fmaf(px[p], a.x, e);
            const float k = __builtin_amdgcn_exp2f(e);
            acc[p].x = fmaf(k, f.x, acc[p].x);
            acc[p].y = fmaf(k, f.y, acc[p].y);
            acc[p].z = fmaf(k, f.z, acc[p].z);
            acc[p].w += k;
        }
    }
#pragma unroll
    for (int p = 0; p < FPPT; ++p) {
        const int n = n0 + threadIdx.x + p * BLOCK;
        const float inv = 1.0f / acc[p].w;
        float* ob = out + b * 3 * N_;
        ob[n]          = acc[p].x * inv;
        ob[N_ + n]     = acc[p].y * inv;
        ob[2 * N_ + n] = acc[p].z * inv;
    }
}

extern "C" void kernel_launch(void* const* d_in, const int* in_sizes, int n_in,
                              void* d_out, int out_size, void* d_ws, size_t ws_size,
                              hipStream_t stream)
{
    const float* xyz   = (const float*)d_in[0];
    const float* sxyz  = (const float*)d_in[1];
    const float* sflow = (const float*)d_in[2];
    const int*   resol = (const int*)d_in[3];
    float* out = (float*)d_out;
    float4* part = (float4*)d_ws;

    const size_t per_chunk = (size_t)BN * sizeof(float4);   // 512 KB
    int SC = 32;
    while (SC > 1 && (size_t)SC * per_chunk > ws_size) SC >>= 1;

    if ((size_t)SC * per_chunk > ws_size) {
        uf2_fused<<<dim3(BN / 1024), dim3(BLOCK), 0, stream>>>(
            xyz, sxyz, sflow, resol, out);
        return;
    }

    dim3 grid(NB * SC), blk(BLOCK);
    switch (SC) {
        case 32: uf2_main<S_ / 32><<<grid, blk, 0, stream>>>(xyz, sxyz, sflow, resol, part); break;
        case 16: uf2_main<S_ / 16><<<grid, blk, 0, stream>>>(xyz, sxyz, sflow, resol, part); break;
        case 8:  uf2_main<S_ / 8 ><<<grid, blk, 0, stream>>>(xyz, sxyz, sflow, resol, part); break;
        case 4:  uf2_main<S_ / 4 ><<<grid, blk, 0, stream>>>(xyz, sxyz, sflow, resol, part); break;
        case 2:  uf2_main<S_ / 2 ><<<grid, blk, 0, stream>>>(xyz, sxyz, sflow, resol, part); break;
        default: uf2_main<S_     ><<<grid, blk, 0, stream>>>(xyz, sxyz, sflow, resol, part); break;
    }
    uf2_combine<<<dim3(BN / BLOCK), dim3(BLOCK), 0, stream>>>(part, out, SC);
}